// Round 1
// baseline (382.811 us; speedup 1.0000x reference)
//
#include <hip/hip_runtime.h>

// GCN: n=100k nodes, E=1.6M edges, D=64, 3 layers.
// Round 9: spmm+gemm fused per layer. 512-thread block owns 128 rows; 8 waves do
// wave-per-row bf16 gather/reduce (32 edges in flight) writing scaled results
// directly into the transposed LDS tile sXT, then the block runs the 128x64 GEMM
// + bias + ReLU + pool + next-layer bf16 cast. agg buffer eliminated; xb is
// double-buffered (a/b) since the fused kernel reads and writes features in one
// dispatch. Preprocessing (scatter/sort/degree/cast) unchanged from round 8.
// Packing (src<<9)|(dst&511) needs n <= 2^17.

#define TPB 256
#define CAPB 16384     // per-bucket slot capacity (92 sigma above mean)
#define CAP_S2 10240   // LDS staging for sorted col; bucket count ~8.2k avg

__device__ __forceinline__ unsigned short f2bf(float f) {   // RNE fp32->bf16
  unsigned u = __float_as_uint(f);
  u += 0x7fff + ((u >> 16) & 1);
  return (unsigned short)(u >> 16);
}
__device__ __forceinline__ float bflo(unsigned u) { return __uint_as_float(u << 16); }
__device__ __forceinline__ float bfhi(unsigned u) { return __uint_as_float(u & 0xffff0000u); }

// ---------------- cursor init: cur[b] = b*CAPB ----------------
__global__ void init_cursors(int* __restrict__ cur_s, int* __restrict__ cur_d) {
  int t = threadIdx.x;
  cur_s[t] = t * CAPB;
  cur_d[t] = t * CAPB;
}

// ---------------- one read pass, two coarse scatters (LDS count -> global reserve) -------------
__global__ __launch_bounds__(256) void scatter_both(
    const int* __restrict__ src, const int* __restrict__ dst, int e,
    int* __restrict__ cur_s, int* __restrict__ cur_d,
    int* __restrict__ srcbuf, unsigned* __restrict__ edges1) {
  __shared__ int hs[256], hd[256];
  int t = threadIdx.x, b = blockIdx.x;
  hs[t] = 0; hd[t] = 0;
  __syncthreads();
  int base = b * 4096;
  int sv[16], dv[16];
  #pragma unroll
  for (int k = 0; k < 4; k++) {
    int i = base + 4 * t + 1024 * k;
    if (i + 3 < e) {
      int4 s4 = *(const int4*)&src[i];
      int4 d4 = *(const int4*)&dst[i];
      sv[4*k] = s4.x; sv[4*k+1] = s4.y; sv[4*k+2] = s4.z; sv[4*k+3] = s4.w;
      dv[4*k] = d4.x; dv[4*k+1] = d4.y; dv[4*k+2] = d4.z; dv[4*k+3] = d4.w;
    } else {
      #pragma unroll
      for (int j = 0; j < 4; j++) {
        int idx = i + j;
        if (idx < e) { sv[4*k+j] = src[idx]; dv[4*k+j] = dst[idx]; }
        else { sv[4*k+j] = -1; dv[4*k+j] = -1; }
      }
    }
  }
  #pragma unroll
  for (int k = 0; k < 16; k++) {
    if (dv[k] >= 0) {
      atomicAdd(&hs[sv[k] >> 9], 1);
      atomicAdd(&hd[dv[k] >> 9], 1);
    }
  }
  __syncthreads();
  int bs = hs[t], bd = hd[t];
  hs[t] = bs ? atomicAdd(&cur_s[t], bs) : 0;
  hd[t] = bd ? atomicAdd(&cur_d[t], bd) : 0;
  __syncthreads();
  #pragma unroll
  for (int k = 0; k < 16; k++) {
    if (dv[k] >= 0) {
      int ps = atomicAdd(&hs[sv[k] >> 9], 1);
      srcbuf[ps] = sv[k];
      int pd = atomicAdd(&hd[dv[k] >> 9], 1);
      edges1[pd] = ((unsigned)sv[k] << 9) | (unsigned)(dv[k] & 511);
    }
  }
}

// ---------------- fused: dst fine-sort (row_beg/row_end/inv_in/col) + out-degree + bf16 cast ----
// block b owns nodes [b*512, b*512+512), src slot [b*CAPB, cur_s[b]), dst slot [b*CAPB, cur_d[b))
__global__ __launch_bounds__(256) void sort_deg_cast(
    const unsigned* __restrict__ edges1, const int* __restrict__ srcbuf,
    const int* __restrict__ cur_s, const int* __restrict__ cur_d,
    const float* __restrict__ node_feat,
    int* __restrict__ row_beg, int* __restrict__ row_end,
    float* __restrict__ inv_in, float* __restrict__ inv_out,
    unsigned short* __restrict__ xb, int* __restrict__ col, int n) {
  __shared__ int sOut[CAP_S2];
  __shared__ int hist[512], cur[512];
  __shared__ int psum[256];
  __shared__ int dhist[512];
  __shared__ float sInv[512];
  int b = blockIdx.x, t = threadIdx.x;
  int sbase = b * CAPB;
  int es = cur_s[b];                  // end of this block's src slot
  int ed = cur_d[b];                  // end of this block's dst slot
  int rstart = b << 9;
  int nrows = min(512, n - rstart);
  hist[t] = 0; hist[t + 256] = 0;
  dhist[t] = 0; dhist[t + 256] = 0;
  __syncthreads();
  for (int i = sbase + t; i < ed; i += TPB) atomicAdd(&hist[edges1[i] & 511u], 1);
  for (int i = sbase + t; i < es; i += TPB) atomicAdd(&dhist[srcbuf[i] & 511], 1);
  __syncthreads();
  // out-degree -> inv_out + LDS copy for the cast below
  #pragma unroll
  for (int k = 0; k < 2; k++) {
    int r = t + k * 256;
    if (r < nrows) {
      float iv = rsqrtf(fmaxf((float)dhist[r], 1.0f));
      sInv[r] = iv;
      inv_out[rstart + r] = iv;
    }
  }
  // in-degree scan -> row_beg/row_end/inv_in + place cursors
  int h0 = hist[2 * t], h1 = hist[2 * t + 1];
  psum[t] = h0 + h1; __syncthreads();
  for (int off = 1; off < 256; off <<= 1) {
    int a = (t >= off) ? psum[t - off] : 0;
    __syncthreads(); psum[t] += a; __syncthreads();
  }
  int ex = psum[t] - (h0 + h1);
  cur[2 * t] = ex; cur[2 * t + 1] = ex + h0;
  if (2 * t < nrows) {
    row_beg[rstart + 2 * t] = sbase + ex;
    row_end[rstart + 2 * t] = sbase + ex + h0;
    inv_in[rstart + 2 * t] = rsqrtf(fmaxf((float)h0, 1.0f));
  }
  if (2 * t + 1 < nrows) {
    row_beg[rstart + 2 * t + 1] = sbase + ex + h0;
    row_end[rstart + 2 * t + 1] = sbase + ex + h0 + h1;
    inv_in[rstart + 2 * t + 1] = rsqrtf(fmaxf((float)h1, 1.0f));
  }
  __syncthreads();
  for (int i = sbase + t; i < ed; i += TPB) {
    unsigned v = edges1[i];
    int pos = atomicAdd(&cur[v & 511u], 1);
    int svv = (int)(v >> 9);
    if (pos < CAP_S2) sOut[pos] = svv;
    else col[sbase + pos] = svv;      // statistically never; correctness fallback
  }
  __syncthreads();
  int m = min(ed - sbase, CAP_S2);
  for (int k = t; k < m; k += TPB) col[sbase + k] = sOut[k];
  // pre-scaled bf16 cast of this block's feature rows (sInv valid since the scan barriers)
  int total4 = nrows * 16;            // 64 feats = 16 float4 per row
  const float* xbase = node_feat + (size_t)rstart * 64;
  unsigned short* obase = xb + (size_t)rstart * 64;
  for (int u = t; u < total4; u += TPB) {
    int r = u >> 4;
    float sc = sInv[r];
    float4 v = *(const float4*)&xbase[(size_t)u * 4];
    ushort4 o;
    o.x = f2bf(v.x * sc); o.y = f2bf(v.y * sc);
    o.z = f2bf(v.z * sc); o.w = f2bf(v.w * sc);
    *(ushort4*)&obase[(size_t)u * 4] = o;
  }
}

// ---------------- fused SpMM + GEMM + bias + ReLU + pool + next-layer bf16 cast ----------------
// 512 threads own 128 rows. Phase 1: 8 waves, wave-per-row gather (32 edges in flight),
// shfl-reduce, scaled store into transposed LDS tile sXT. Phase 2: 128x64 @ 64x64 GEMM
// from LDS with epilogue. agg never touches global memory.
__global__ __launch_bounds__(512) void spmm_gemm(
    const unsigned short* __restrict__ xb,
    const int* __restrict__ row_beg, const int* __restrict__ row_end,
    const int* __restrict__ col,
    const float* __restrict__ inv_in, const float* __restrict__ inv_out,
    const float* __restrict__ W, const float* __restrict__ bias,
    float* __restrict__ out_cat, float* __restrict__ out_pool,
    unsigned short* __restrict__ xb_next, int n) {
  __shared__ float sW[64 * 64];
  __shared__ float sXT[64][132];      // [feat][row], pad 132 keeps float4 reads aligned
  int t = threadIdx.x;
  int row0 = blockIdx.x << 7;
  // stage W (overlaps with the latency-bound gather phase below)
  for (int i4 = t * 4; i4 < 4096; i4 += 2048)
    *(float4*)&sW[i4] = *(const float4*)&W[i4];
  int lane = t & 63;
  int g = lane >> 3;            // edge group 0..7
  int l8 = (lane & 7) << 3;     // feature offset (8 feats = 16 B)
  int wv = t >> 6;              // wave 0..7, each owns 16 rows
  for (int k = 0; k < 16; k++) {
    int rl = wv * 16 + k;
    int row = row0 + rl;
    float v = 0.f;
    if (row < n) {              // wave-uniform branch
      float a0 = 0, a1 = 0, a2 = 0, a3 = 0, a4 = 0, a5 = 0, a6 = 0, a7 = 0;
      int s = row_beg[row], e = row_end[row];
      for (int i = s + g; i < e; i += 32) {   // 32 edges in flight per wave
        int ec = e - 1;
        int i1 = i + 8, i2 = i + 16, i3 = i + 24;
        int c0 = col[i];
        int c1 = col[min(i1, ec)];
        int c2 = col[min(i2, ec)];
        int c3 = col[min(i3, ec)];
        float m1 = (i1 < e) ? 1.f : 0.f;
        float m2 = (i2 < e) ? 1.f : 0.f;
        float m3 = (i3 < e) ? 1.f : 0.f;
        uint4 r0 = *(const uint4*)&xb[(size_t)c0 * 64 + l8];
        uint4 r1 = *(const uint4*)&xb[(size_t)c1 * 64 + l8];
        uint4 r2 = *(const uint4*)&xb[(size_t)c2 * 64 + l8];
        uint4 r3 = *(const uint4*)&xb[(size_t)c3 * 64 + l8];
        a0 += bflo(r0.x); a1 += bfhi(r0.x); a2 += bflo(r0.y); a3 += bfhi(r0.y);
        a4 += bflo(r0.z); a5 += bfhi(r0.z); a6 += bflo(r0.w); a7 += bfhi(r0.w);
        a0 = fmaf(m1, bflo(r1.x), a0); a1 = fmaf(m1, bfhi(r1.x), a1);
        a2 = fmaf(m1, bflo(r1.y), a2); a3 = fmaf(m1, bfhi(r1.y), a3);
        a4 = fmaf(m1, bflo(r1.z), a4); a5 = fmaf(m1, bfhi(r1.z), a5);
        a6 = fmaf(m1, bflo(r1.w), a6); a7 = fmaf(m1, bfhi(r1.w), a7);
        a0 = fmaf(m2, bflo(r2.x), a0); a1 = fmaf(m2, bfhi(r2.x), a1);
        a2 = fmaf(m2, bflo(r2.y), a2); a3 = fmaf(m2, bfhi(r2.y), a3);
        a4 = fmaf(m2, bflo(r2.z), a4); a5 = fmaf(m2, bfhi(r2.z), a5);
        a6 = fmaf(m2, bflo(r2.w), a6); a7 = fmaf(m2, bfhi(r2.w), a7);
        a0 = fmaf(m3, bflo(r3.x), a0); a1 = fmaf(m3, bfhi(r3.x), a1);
        a2 = fmaf(m3, bflo(r3.y), a2); a3 = fmaf(m3, bfhi(r3.y), a3);
        a4 = fmaf(m3, bflo(r3.z), a4); a5 = fmaf(m3, bfhi(r3.z), a5);
        a6 = fmaf(m3, bflo(r3.w), a6); a7 = fmaf(m3, bfhi(r3.w), a7);
      }
      // butterfly over edge groups (bits 3..5 of lane): all lanes end with full sums
      a0 += __shfl_xor(a0, 8); a0 += __shfl_xor(a0, 16); a0 += __shfl_xor(a0, 32);
      a1 += __shfl_xor(a1, 8); a1 += __shfl_xor(a1, 16); a1 += __shfl_xor(a1, 32);
      a2 += __shfl_xor(a2, 8); a2 += __shfl_xor(a2, 16); a2 += __shfl_xor(a2, 32);
      a3 += __shfl_xor(a3, 8); a3 += __shfl_xor(a3, 16); a3 += __shfl_xor(a3, 32);
      a4 += __shfl_xor(a4, 8); a4 += __shfl_xor(a4, 16); a4 += __shfl_xor(a4, 32);
      a5 += __shfl_xor(a5, 8); a5 += __shfl_xor(a5, 16); a5 += __shfl_xor(a5, 32);
      a6 += __shfl_xor(a6, 8); a6 += __shfl_xor(a6, 16); a6 += __shfl_xor(a6, 32);
      a7 += __shfl_xor(a7, 8); a7 += __shfl_xor(a7, 16); a7 += __shfl_xor(a7, 32);
      // lane (g,l8) contributes feature f = l8 + g (cndmask tree, no scratch array)
      float s0 = (g & 1) ? a1 : a0;
      float s1 = (g & 1) ? a3 : a2;
      float s2 = (g & 1) ? a5 : a4;
      float s3 = (g & 1) ? a7 : a6;
      float u0 = (g & 2) ? s1 : s0;
      float u1 = (g & 2) ? s3 : s2;
      v = ((g & 4) ? u1 : u0) * inv_in[row];
    }
    sXT[l8 + g][rl] = v;        // 64 lanes -> 64 feats of column rl (8-way, single store)
  }
  __syncthreads();
  // ---- GEMM phase: 512 threads, 4x4 micro-tile each -> 128 rows x 64 cols ----
  int tj = t & 15, tr = t >> 4;
  int j4 = tj << 2, r4 = tr << 2;
  const float4 bv = *(const float4*)&bias[j4];
  float4 a0 = bv, a1 = bv, a2 = bv, a3 = bv;
  #pragma unroll 8
  for (int f = 0; f < 64; f++) {
    float4 w  = *(const float4*)&sW[f * 64 + j4];
    float4 xv = *(const float4*)&sXT[f][r4];
    a0.x = fmaf(xv.x, w.x, a0.x); a0.y = fmaf(xv.x, w.y, a0.y);
    a0.z = fmaf(xv.x, w.z, a0.z); a0.w = fmaf(xv.x, w.w, a0.w);
    a1.x = fmaf(xv.y, w.x, a1.x); a1.y = fmaf(xv.y, w.y, a1.y);
    a1.z = fmaf(xv.y, w.z, a1.z); a1.w = fmaf(xv.y, w.w, a1.w);
    a2.x = fmaf(xv.z, w.x, a2.x); a2.y = fmaf(xv.z, w.y, a2.y);
    a2.z = fmaf(xv.z, w.z, a2.z); a2.w = fmaf(xv.z, w.w, a2.w);
    a3.x = fmaf(xv.w, w.x, a3.x); a3.y = fmaf(xv.w, w.y, a3.y);
    a3.z = fmaf(xv.w, w.z, a3.z); a3.w = fmaf(xv.w, w.w, a3.w);
  }
  float4 accs[4] = {a0, a1, a2, a3};
  #pragma unroll
  for (int ri = 0; ri < 4; ri++) {
    int row = row0 + r4 + ri;
    if (row < n) {
      float4 h = accs[ri];
      h.x = fmaxf(h.x, 0.f); h.y = fmaxf(h.y, 0.f);
      h.z = fmaxf(h.z, 0.f); h.w = fmaxf(h.w, 0.f);
      *(float4*)&out_cat[(size_t)row * 192 + j4] = h;
      if (xb_next) {
        float sc = inv_out[row];
        ushort4 o;
        o.x = f2bf(h.x * sc); o.y = f2bf(h.y * sc);
        o.z = f2bf(h.z * sc); o.w = f2bf(h.w * sc);
        *(ushort4*)&xb_next[(size_t)row * 64 + j4] = o;
      }
      float part = h.x + h.y + h.z + h.w;
      part += __shfl_xor(part, 1);
      part += __shfl_xor(part, 2);
      part += __shfl_xor(part, 4);
      part += __shfl_xor(part, 8);
      if (tj == 0) out_pool[row] = part;
    }
  }
}

// ---------------- launch ----------------

extern "C" void kernel_launch(void* const* d_in, const int* in_sizes, int n_in,
                              void* d_out, int out_size, void* d_ws, size_t ws_size,
                              hipStream_t stream) {
  const float* node_feat = (const float*)d_in[0];
  const int* src = (const int*)d_in[1];
  const int* dst = (const int*)d_in[2];
  const float* Ws[3] = {(const float*)d_in[4], (const float*)d_in[6], (const float*)d_in[8]};
  const float* bs[3] = {(const float*)d_in[5], (const float*)d_in[7], (const float*)d_in[9]};
  float* out = (float*)d_out;
  int n = in_sizes[0] / 64;
  int e = in_sizes[1];
  int nbb = (n + 511) >> 9;         // coarse buckets (196 for n=100k)
  int nblk = (e + 4095) / 4096;     // edge blocks (391)
  size_t slots = (size_t)nbb * CAPB;

  char* p = (char*)d_ws;
  unsigned short* xba = (unsigned short*)p; p += (size_t)n * 64 * sizeof(unsigned short);
  unsigned short* xbb = (unsigned short*)p; p += (size_t)n * 64 * sizeof(unsigned short);
  float* inv_out = (float*)p;   p += (size_t)n * sizeof(float);
  float* inv_in = (float*)p;    p += (size_t)n * sizeof(float);
  int* row_beg = (int*)p;       p += (size_t)n * sizeof(int);
  int* row_end = (int*)p;       p += (size_t)n * sizeof(int);
  int* cur_s = (int*)p;         p += 256 * sizeof(int);
  int* cur_d = (int*)p;         p += 256 * sizeof(int);
  unsigned* edges1 = (unsigned*)p; p += slots * sizeof(unsigned);
  int* srcbuf = (int*)p;        p += slots * sizeof(int);
  int* col = (int*)p;           p += slots * sizeof(int);

  init_cursors<<<1, 256, 0, stream>>>(cur_s, cur_d);
  scatter_both<<<nblk, TPB, 0, stream>>>(src, dst, e, cur_s, cur_d, srcbuf, edges1);
  sort_deg_cast<<<nbb, TPB, 0, stream>>>(edges1, srcbuf, cur_s, cur_d, node_feat,
                                         row_beg, row_end, inv_in, inv_out, xba, col, n);

  float* cat_base = out + (size_t)3 * n;
  int nfb = (n + 127) >> 7;         // fused blocks: 128 rows each (782 for n=100k)
  // xb double-buffered: fused kernel reads features while writing next layer's.
  spmm_gemm<<<nfb, 512, 0, stream>>>(xba, row_beg, row_end, col, inv_in, inv_out,
      Ws[0], bs[0], cat_base + 0 * 64, out + (size_t)0 * n, xbb, n);
  spmm_gemm<<<nfb, 512, 0, stream>>>(xbb, row_beg, row_end, col, inv_in, inv_out,
      Ws[1], bs[1], cat_base + 1 * 64, out + (size_t)1 * n, xba, n);
  spmm_gemm<<<nfb, 512, 0, stream>>>(xba, row_beg, row_end, col, inv_in, inv_out,
      Ws[2], bs[2], cat_base + 2 * 64, out + (size_t)2 * n, (unsigned short*)nullptr, n);
}

// Round 2
// 353.970 us; speedup vs baseline: 1.0815x; 1.0815x over previous
//
#include <hip/hip_runtime.h>

// GCN: n=100k nodes, E=1.6M edges, D=64, 3 layers.
// Round 10: fused spmm+gemm per layer, occupancy-fixed. Round-9 counters showed
// Occupancy 36% / VALUBusy 48% -> VALU-issue-bound gather starved of waves by the
// 50 KB LDS footprint. Fix: drop the sW LDS stage (W is 16 KB, L1/L2-resident,
// read from global in the GEMM loop) -> LDS 33.8 KB -> 4 blocks/CU = 32 waves/CU.
// Everything else unchanged from round 9. Packing (src<<9)|(dst&511) needs n <= 2^17.

#define TPB 256
#define CAPB 16384     // per-bucket slot capacity (92 sigma above mean)
#define CAP_S2 10240   // LDS staging for sorted col; bucket count ~8.2k avg

__device__ __forceinline__ unsigned short f2bf(float f) {   // RNE fp32->bf16
  unsigned u = __float_as_uint(f);
  u += 0x7fff + ((u >> 16) & 1);
  return (unsigned short)(u >> 16);
}
__device__ __forceinline__ float bflo(unsigned u) { return __uint_as_float(u << 16); }
__device__ __forceinline__ float bfhi(unsigned u) { return __uint_as_float(u & 0xffff0000u); }

// ---------------- cursor init: cur[b] = b*CAPB ----------------
__global__ void init_cursors(int* __restrict__ cur_s, int* __restrict__ cur_d) {
  int t = threadIdx.x;
  cur_s[t] = t * CAPB;
  cur_d[t] = t * CAPB;
}

// ---------------- one read pass, two coarse scatters (LDS count -> global reserve) -------------
__global__ __launch_bounds__(256) void scatter_both(
    const int* __restrict__ src, const int* __restrict__ dst, int e,
    int* __restrict__ cur_s, int* __restrict__ cur_d,
    int* __restrict__ srcbuf, unsigned* __restrict__ edges1) {
  __shared__ int hs[256], hd[256];
  int t = threadIdx.x, b = blockIdx.x;
  hs[t] = 0; hd[t] = 0;
  __syncthreads();
  int base = b * 4096;
  int sv[16], dv[16];
  #pragma unroll
  for (int k = 0; k < 4; k++) {
    int i = base + 4 * t + 1024 * k;
    if (i + 3 < e) {
      int4 s4 = *(const int4*)&src[i];
      int4 d4 = *(const int4*)&dst[i];
      sv[4*k] = s4.x; sv[4*k+1] = s4.y; sv[4*k+2] = s4.z; sv[4*k+3] = s4.w;
      dv[4*k] = d4.x; dv[4*k+1] = d4.y; dv[4*k+2] = d4.z; dv[4*k+3] = d4.w;
    } else {
      #pragma unroll
      for (int j = 0; j < 4; j++) {
        int idx = i + j;
        if (idx < e) { sv[4*k+j] = src[idx]; dv[4*k+j] = dst[idx]; }
        else { sv[4*k+j] = -1; dv[4*k+j] = -1; }
      }
    }
  }
  #pragma unroll
  for (int k = 0; k < 16; k++) {
    if (dv[k] >= 0) {
      atomicAdd(&hs[sv[k] >> 9], 1);
      atomicAdd(&hd[dv[k] >> 9], 1);
    }
  }
  __syncthreads();
  int bs = hs[t], bd = hd[t];
  hs[t] = bs ? atomicAdd(&cur_s[t], bs) : 0;
  hd[t] = bd ? atomicAdd(&cur_d[t], bd) : 0;
  __syncthreads();
  #pragma unroll
  for (int k = 0; k < 16; k++) {
    if (dv[k] >= 0) {
      int ps = atomicAdd(&hs[sv[k] >> 9], 1);
      srcbuf[ps] = sv[k];
      int pd = atomicAdd(&hd[dv[k] >> 9], 1);
      edges1[pd] = ((unsigned)sv[k] << 9) | (unsigned)(dv[k] & 511);
    }
  }
}

// ---------------- fused: dst fine-sort (row_beg/row_end/inv_in/col) + out-degree + bf16 cast ----
// block b owns nodes [b*512, b*512+512), src slot [b*CAPB, cur_s[b]), dst slot [b*CAPB, cur_d[b))
__global__ __launch_bounds__(256) void sort_deg_cast(
    const unsigned* __restrict__ edges1, const int* __restrict__ srcbuf,
    const int* __restrict__ cur_s, const int* __restrict__ cur_d,
    const float* __restrict__ node_feat,
    int* __restrict__ row_beg, int* __restrict__ row_end,
    float* __restrict__ inv_in, float* __restrict__ inv_out,
    unsigned short* __restrict__ xb, int* __restrict__ col, int n) {
  __shared__ int sOut[CAP_S2];
  __shared__ int hist[512], cur[512];
  __shared__ int psum[256];
  __shared__ int dhist[512];
  __shared__ float sInv[512];
  int b = blockIdx.x, t = threadIdx.x;
  int sbase = b * CAPB;
  int es = cur_s[b];                  // end of this block's src slot
  int ed = cur_d[b];                  // end of this block's dst slot
  int rstart = b << 9;
  int nrows = min(512, n - rstart);
  hist[t] = 0; hist[t + 256] = 0;
  dhist[t] = 0; dhist[t + 256] = 0;
  __syncthreads();
  for (int i = sbase + t; i < ed; i += TPB) atomicAdd(&hist[edges1[i] & 511u], 1);
  for (int i = sbase + t; i < es; i += TPB) atomicAdd(&dhist[srcbuf[i] & 511], 1);
  __syncthreads();
  // out-degree -> inv_out + LDS copy for the cast below
  #pragma unroll
  for (int k = 0; k < 2; k++) {
    int r = t + k * 256;
    if (r < nrows) {
      float iv = rsqrtf(fmaxf((float)dhist[r], 1.0f));
      sInv[r] = iv;
      inv_out[rstart + r] = iv;
    }
  }
  // in-degree scan -> row_beg/row_end/inv_in + place cursors
  int h0 = hist[2 * t], h1 = hist[2 * t + 1];
  psum[t] = h0 + h1; __syncthreads();
  for (int off = 1; off < 256; off <<= 1) {
    int a = (t >= off) ? psum[t - off] : 0;
    __syncthreads(); psum[t] += a; __syncthreads();
  }
  int ex = psum[t] - (h0 + h1);
  cur[2 * t] = ex; cur[2 * t + 1] = ex + h0;
  if (2 * t < nrows) {
    row_beg[rstart + 2 * t] = sbase + ex;
    row_end[rstart + 2 * t] = sbase + ex + h0;
    inv_in[rstart + 2 * t] = rsqrtf(fmaxf((float)h0, 1.0f));
  }
  if (2 * t + 1 < nrows) {
    row_beg[rstart + 2 * t + 1] = sbase + ex + h0;
    row_end[rstart + 2 * t + 1] = sbase + ex + h0 + h1;
    inv_in[rstart + 2 * t + 1] = rsqrtf(fmaxf((float)h1, 1.0f));
  }
  __syncthreads();
  for (int i = sbase + t; i < ed; i += TPB) {
    unsigned v = edges1[i];
    int pos = atomicAdd(&cur[v & 511u], 1);
    int svv = (int)(v >> 9);
    if (pos < CAP_S2) sOut[pos] = svv;
    else col[sbase + pos] = svv;      // statistically never; correctness fallback
  }
  __syncthreads();
  int m = min(ed - sbase, CAP_S2);
  for (int k = t; k < m; k += TPB) col[sbase + k] = sOut[k];
  // pre-scaled bf16 cast of this block's feature rows (sInv valid since the scan barriers)
  int total4 = nrows * 16;            // 64 feats = 16 float4 per row
  const float* xbase = node_feat + (size_t)rstart * 64;
  unsigned short* obase = xb + (size_t)rstart * 64;
  for (int u = t; u < total4; u += TPB) {
    int r = u >> 4;
    float sc = sInv[r];
    float4 v = *(const float4*)&xbase[(size_t)u * 4];
    ushort4 o;
    o.x = f2bf(v.x * sc); o.y = f2bf(v.y * sc);
    o.z = f2bf(v.z * sc); o.w = f2bf(v.w * sc);
    *(ushort4*)&obase[(size_t)u * 4] = o;
  }
}

// ---------------- fused SpMM + GEMM + bias + ReLU + pool + next-layer bf16 cast ----------------
// 512 threads own 128 rows. Phase 1: 8 waves, wave-per-row gather (32 edges in flight),
// shfl-reduce, scaled store into transposed LDS tile sXT. Phase 2: 128x64 @ 64x64 GEMM
// (W direct from global: 16 KB, L1/L2-resident across all 782 blocks) with epilogue.
// LDS = sXT only (33.8 KB) -> 4 blocks/CU -> 32 waves/CU.
__global__ __launch_bounds__(512) void spmm_gemm(
    const unsigned short* __restrict__ xb,
    const int* __restrict__ row_beg, const int* __restrict__ row_end,
    const int* __restrict__ col,
    const float* __restrict__ inv_in, const float* __restrict__ inv_out,
    const float* __restrict__ W, const float* __restrict__ bias,
    float* __restrict__ out_cat, float* __restrict__ out_pool,
    unsigned short* __restrict__ xb_next, int n) {
  __shared__ float sXT[64][132];      // [feat][row], pad 132 keeps float4 reads aligned
  int t = threadIdx.x;
  int row0 = blockIdx.x << 7;
  int lane = t & 63;
  int g = lane >> 3;            // edge group 0..7
  int l8 = (lane & 7) << 3;     // feature offset (8 feats = 16 B)
  int wv = t >> 6;              // wave 0..7, each owns 16 rows
  for (int k = 0; k < 16; k++) {
    int rl = wv * 16 + k;
    int row = row0 + rl;
    float v = 0.f;
    if (row < n) {              // wave-uniform branch
      int s = row_beg[row], e = row_end[row];
      float inv = inv_in[row];  // hoisted: overlaps with the edge loop below
      float a0 = 0, a1 = 0, a2 = 0, a3 = 0, a4 = 0, a5 = 0, a6 = 0, a7 = 0;
      for (int i = s + g; i < e; i += 32) {   // 32 edges in flight per wave
        int ec = e - 1;
        int i1 = i + 8, i2 = i + 16, i3 = i + 24;
        int c0 = col[i];
        int c1 = col[min(i1, ec)];
        int c2 = col[min(i2, ec)];
        int c3 = col[min(i3, ec)];
        float m1 = (i1 < e) ? 1.f : 0.f;
        float m2 = (i2 < e) ? 1.f : 0.f;
        float m3 = (i3 < e) ? 1.f : 0.f;
        uint4 r0 = *(const uint4*)&xb[(size_t)c0 * 64 + l8];
        uint4 r1 = *(const uint4*)&xb[(size_t)c1 * 64 + l8];
        uint4 r2 = *(const uint4*)&xb[(size_t)c2 * 64 + l8];
        uint4 r3 = *(const uint4*)&xb[(size_t)c3 * 64 + l8];
        a0 += bflo(r0.x); a1 += bfhi(r0.x); a2 += bflo(r0.y); a3 += bfhi(r0.y);
        a4 += bflo(r0.z); a5 += bfhi(r0.z); a6 += bflo(r0.w); a7 += bfhi(r0.w);
        a0 = fmaf(m1, bflo(r1.x), a0); a1 = fmaf(m1, bfhi(r1.x), a1);
        a2 = fmaf(m1, bflo(r1.y), a2); a3 = fmaf(m1, bfhi(r1.y), a3);
        a4 = fmaf(m1, bflo(r1.z), a4); a5 = fmaf(m1, bfhi(r1.z), a5);
        a6 = fmaf(m1, bflo(r1.w), a6); a7 = fmaf(m1, bfhi(r1.w), a7);
        a0 = fmaf(m2, bflo(r2.x), a0); a1 = fmaf(m2, bfhi(r2.x), a1);
        a2 = fmaf(m2, bflo(r2.y), a2); a3 = fmaf(m2, bfhi(r2.y), a3);
        a4 = fmaf(m2, bflo(r2.z), a4); a5 = fmaf(m2, bfhi(r2.z), a5);
        a6 = fmaf(m2, bflo(r2.w), a6); a7 = fmaf(m2, bfhi(r2.w), a7);
        a0 = fmaf(m3, bflo(r3.x), a0); a1 = fmaf(m3, bfhi(r3.x), a1);
        a2 = fmaf(m3, bflo(r3.y), a2); a3 = fmaf(m3, bfhi(r3.y), a3);
        a4 = fmaf(m3, bflo(r3.z), a4); a5 = fmaf(m3, bfhi(r3.z), a5);
        a6 = fmaf(m3, bflo(r3.w), a6); a7 = fmaf(m3, bfhi(r3.w), a7);
      }
      // butterfly over edge groups (bits 3..5 of lane): all lanes end with full sums
      a0 += __shfl_xor(a0, 8); a0 += __shfl_xor(a0, 16); a0 += __shfl_xor(a0, 32);
      a1 += __shfl_xor(a1, 8); a1 += __shfl_xor(a1, 16); a1 += __shfl_xor(a1, 32);
      a2 += __shfl_xor(a2, 8); a2 += __shfl_xor(a2, 16); a2 += __shfl_xor(a2, 32);
      a3 += __shfl_xor(a3, 8); a3 += __shfl_xor(a3, 16); a3 += __shfl_xor(a3, 32);
      a4 += __shfl_xor(a4, 8); a4 += __shfl_xor(a4, 16); a4 += __shfl_xor(a4, 32);
      a5 += __shfl_xor(a5, 8); a5 += __shfl_xor(a5, 16); a5 += __shfl_xor(a5, 32);
      a6 += __shfl_xor(a6, 8); a6 += __shfl_xor(a6, 16); a6 += __shfl_xor(a6, 32);
      a7 += __shfl_xor(a7, 8); a7 += __shfl_xor(a7, 16); a7 += __shfl_xor(a7, 32);
      // lane (g,l8) contributes feature f = l8 + g (cndmask tree, no scratch array)
      float s0 = (g & 1) ? a1 : a0;
      float s1 = (g & 1) ? a3 : a2;
      float s2 = (g & 1) ? a5 : a4;
      float s3 = (g & 1) ? a7 : a6;
      float u0 = (g & 2) ? s1 : s0;
      float u1 = (g & 2) ? s3 : s2;
      v = ((g & 4) ? u1 : u0) * inv;
    }
    sXT[l8 + g][rl] = v;        // 64 lanes -> 64 feats of column rl (8-way, single store)
  }
  __syncthreads();
  // ---- GEMM phase: 512 threads, 4x4 micro-tile each -> 128 rows x 64 cols ----
  int tj = t & 15, tr = t >> 4;
  int j4 = tj << 2, r4 = tr << 2;
  const float4 bv = *(const float4*)&bias[j4];
  float4 a0 = bv, a1 = bv, a2 = bv, a3 = bv;
  #pragma unroll 8
  for (int f = 0; f < 64; f++) {
    float4 w  = *(const float4*)&W[f * 64 + j4];   // L1-resident after first block
    float4 xv = *(const float4*)&sXT[f][r4];
    a0.x = fmaf(xv.x, w.x, a0.x); a0.y = fmaf(xv.x, w.y, a0.y);
    a0.z = fmaf(xv.x, w.z, a0.z); a0.w = fmaf(xv.x, w.w, a0.w);
    a1.x = fmaf(xv.y, w.x, a1.x); a1.y = fmaf(xv.y, w.y, a1.y);
    a1.z = fmaf(xv.y, w.z, a1.z); a1.w = fmaf(xv.y, w.w, a1.w);
    a2.x = fmaf(xv.z, w.x, a2.x); a2.y = fmaf(xv.z, w.y, a2.y);
    a2.z = fmaf(xv.z, w.z, a2.z); a2.w = fmaf(xv.z, w.w, a2.w);
    a3.x = fmaf(xv.w, w.x, a3.x); a3.y = fmaf(xv.w, w.y, a3.y);
    a3.z = fmaf(xv.w, w.z, a3.z); a3.w = fmaf(xv.w, w.w, a3.w);
  }
  float4 accs[4] = {a0, a1, a2, a3};
  #pragma unroll
  for (int ri = 0; ri < 4; ri++) {
    int row = row0 + r4 + ri;
    if (row < n) {
      float4 h = accs[ri];
      h.x = fmaxf(h.x, 0.f); h.y = fmaxf(h.y, 0.f);
      h.z = fmaxf(h.z, 0.f); h.w = fmaxf(h.w, 0.f);
      *(float4*)&out_cat[(size_t)row * 192 + j4] = h;
      if (xb_next) {
        float sc = inv_out[row];
        ushort4 o;
        o.x = f2bf(h.x * sc); o.y = f2bf(h.y * sc);
        o.z = f2bf(h.z * sc); o.w = f2bf(h.w * sc);
        *(ushort4*)&xb_next[(size_t)row * 64 + j4] = o;
      }
      float part = h.x + h.y + h.z + h.w;
      part += __shfl_xor(part, 1);
      part += __shfl_xor(part, 2);
      part += __shfl_xor(part, 4);
      part += __shfl_xor(part, 8);
      if (tj == 0) out_pool[row] = part;
    }
  }
}

// ---------------- launch ----------------

extern "C" void kernel_launch(void* const* d_in, const int* in_sizes, int n_in,
                              void* d_out, int out_size, void* d_ws, size_t ws_size,
                              hipStream_t stream) {
  const float* node_feat = (const float*)d_in[0];
  const int* src = (const int*)d_in[1];
  const int* dst = (const int*)d_in[2];
  const float* Ws[3] = {(const float*)d_in[4], (const float*)d_in[6], (const float*)d_in[8]};
  const float* bs[3] = {(const float*)d_in[5], (const float*)d_in[7], (const float*)d_in[9]};
  float* out = (float*)d_out;
  int n = in_sizes[0] / 64;
  int e = in_sizes[1];
  int nbb = (n + 511) >> 9;         // coarse buckets (196 for n=100k)
  int nblk = (e + 4095) / 4096;     // edge blocks (391)
  size_t slots = (size_t)nbb * CAPB;

  char* p = (char*)d_ws;
  unsigned short* xba = (unsigned short*)p; p += (size_t)n * 64 * sizeof(unsigned short);
  unsigned short* xbb = (unsigned short*)p; p += (size_t)n * 64 * sizeof(unsigned short);
  float* inv_out = (float*)p;   p += (size_t)n * sizeof(float);
  float* inv_in = (float*)p;    p += (size_t)n * sizeof(float);
  int* row_beg = (int*)p;       p += (size_t)n * sizeof(int);
  int* row_end = (int*)p;       p += (size_t)n * sizeof(int);
  int* cur_s = (int*)p;         p += 256 * sizeof(int);
  int* cur_d = (int*)p;         p += 256 * sizeof(int);
  unsigned* edges1 = (unsigned*)p; p += slots * sizeof(unsigned);
  int* srcbuf = (int*)p;        p += slots * sizeof(int);
  int* col = (int*)p;           p += slots * sizeof(int);

  init_cursors<<<1, 256, 0, stream>>>(cur_s, cur_d);
  scatter_both<<<nblk, TPB, 0, stream>>>(src, dst, e, cur_s, cur_d, srcbuf, edges1);
  sort_deg_cast<<<nbb, TPB, 0, stream>>>(edges1, srcbuf, cur_s, cur_d, node_feat,
                                         row_beg, row_end, inv_in, inv_out, xba, col, n);

  float* cat_base = out + (size_t)3 * n;
  int nfb = (n + 127) >> 7;         // fused blocks: 128 rows each (782 for n=100k)
  // xb double-buffered: fused kernel reads features while writing next layer's.
  spmm_gemm<<<nfb, 512, 0, stream>>>(xba, row_beg, row_end, col, inv_in, inv_out,
      Ws[0], bs[0], cat_base + 0 * 64, out + (size_t)0 * n, xbb, n);
  spmm_gemm<<<nfb, 512, 0, stream>>>(xbb, row_beg, row_end, col, inv_in, inv_out,
      Ws[1], bs[1], cat_base + 1 * 64, out + (size_t)1 * n, xba, n);
  spmm_gemm<<<nfb, 512, 0, stream>>>(xba, row_beg, row_end, col, inv_in, inv_out,
      Ws[2], bs[2], cat_base + 2 * 64, out + (size_t)2 * n, (unsigned short*)nullptr, n);
}